// Round 1
// baseline (243.974 us; speedup 1.0000x reference)
//
#include <hip/hip_runtime.h>
#include <cstdint>

// Problem constants
#define N_TOK 4096   // B*T
#define D_    1024
#define E_    8
#define I_    512
#define KTOP  2
#define BM    64     // position-tile (expert segments padded to BM)
#define BK    64     // K-step
#define CAP   (N_TOK*KTOP + E_*BM)   // 8704 max padded positions

typedef __attribute__((ext_vector_type(4))) float f32x4;
typedef __attribute__((ext_vector_type(8))) short bf16x8;

__device__ inline unsigned short f2bf(float f) {
  union { float f; uint32_t u; } v; v.f = f;
  uint32_t r = v.u + 0x7fffu + ((v.u >> 16) & 1u);
  return (unsigned short)(r >> 16);
}

// global -> LDS direct copy, 16B per lane. LDS dest is wave-uniform base,
// lane l lands at base + l*16 (m104). Global src is per-lane (enables the
// pre-swizzled-source trick, m173).
#define GLOAD_LDS16(gp, lp)                                                        \
  __builtin_amdgcn_global_load_lds((const __attribute__((address_space(1))) void*)(gp), \
                                   (__attribute__((address_space(3))) void*)(lp), 16, 0, 0)

// ---------------- fp32 -> bf16 convert (vectorized) ----------------
__global__ __launch_bounds__(256) void convert_kernel(const float* __restrict__ src,
                                                      unsigned short* __restrict__ dst,
                                                      int n4) {
  int i = blockIdx.x * 256 + threadIdx.x;
  if (i >= n4) return;
  const float4 v = reinterpret_cast<const float4*>(src)[i];
  ushort4 o;
  o.x = f2bf(v.x); o.y = f2bf(v.y); o.z = f2bf(v.z); o.w = f2bf(v.w);
  reinterpret_cast<ushort4*>(dst)[i] = o;
}

// ---------------- router: logits (fp32), top-2, softmax, counts ----------------
__global__ __launch_bounds__(256) void router_kernel(const float* __restrict__ x,
                                                     const float* __restrict__ rw,
                                                     float* __restrict__ logits,
                                                     int* __restrict__ sel,
                                                     float* __restrict__ prob,
                                                     int* __restrict__ counts) {
  const int lane = threadIdx.x & 63;
  const int tok  = blockIdx.x * 4 + (threadIdx.x >> 6);
  const float4* xr = reinterpret_cast<const float4*>(x + (size_t)tok * D_);
  float4 xv[4];
#pragma unroll
  for (int q = 0; q < 4; ++q) xv[q] = xr[lane * 4 + q];
  float acc[E_];
#pragma unroll
  for (int e = 0; e < E_; ++e) {
    const float4* wr = reinterpret_cast<const float4*>(rw + (size_t)e * D_);
    float s = 0.f;
#pragma unroll
    for (int q = 0; q < 4; ++q) {
      float4 wv = wr[lane * 4 + q];
      s += xv[q].x * wv.x + xv[q].y * wv.y + xv[q].z * wv.z + xv[q].w * wv.w;
    }
    acc[e] = s;
  }
#pragma unroll
  for (int e = 0; e < E_; ++e)
#pragma unroll
    for (int off = 32; off; off >>= 1) acc[e] += __shfl_xor(acc[e], off);
  if (lane == 0) {
    float v0 = -1e30f, v1 = -1e30f; int i0 = 0, i1 = 0;
#pragma unroll
    for (int e = 0; e < E_; ++e) {
      float v = acc[e];
      logits[(size_t)tok * E_ + e] = v;
      if (v > v0)      { v1 = v0; i1 = i0; v0 = v; i0 = e; }
      else if (v > v1) { v1 = v;  i1 = e; }
    }
    float t  = __expf(v1 - v0);
    float p0 = 1.f / (1.f + t);
    float p1 = t / (1.f + t);
    sel[tok * 2] = i0; sel[tok * 2 + 1] = i1;
    prob[tok * 2] = p0; prob[tok * 2 + 1] = p1;
    atomicAdd(&counts[i0], 1);
    atomicAdd(&counts[i1], 1);
  }
}

// ---------------- padded exclusive scan of counts ----------------
__global__ void offsets_kernel(const int* __restrict__ counts, int* __restrict__ offs) {
  if (threadIdx.x == 0 && blockIdx.x == 0) {
    int run = 0;
    for (int e = 0; e < E_; ++e) { offs[e] = run; run += (counts[e] + BM - 1) & ~(BM - 1); }
    offs[E_] = run;
  }
}

// ---------------- scatter (token,slot) -> expert-sorted position ----------------
__global__ __launch_bounds__(256) void scatter_kernel(const int* __restrict__ sel,
                                                      const float* __restrict__ prob,
                                                      const int* __restrict__ offs,
                                                      int* __restrict__ cursor,
                                                      int* __restrict__ ptok,
                                                      float* __restrict__ pprob) {
  int i = blockIdx.x * 256 + threadIdx.x;  // 0..8191
  int e = sel[i];
  int p = atomicAdd(&cursor[e], 1);
  int pos = offs[e] + p;
  ptok[pos]  = i >> 1;
  pprob[pos] = prob[i];
}

// ---------------- GEMM1: H = silu(X Wg^T) * (X Wu^T), per expert segment ----------------
// A: gathered X rows [BM x 1024] bf16; B: Wg/Wu rows [128 x 1024] ([N,K] layout).
// 4 waves in 2x2 over 64x128 tile; 16x16x32 bf16 MFMA; XOR-swizzled LDS
// (pre-swizzled global source keeps global_load_lds dest linear).
__global__ __launch_bounds__(256) void gemm1_kernel(const unsigned short* __restrict__ Xb,
                                                    const unsigned short* __restrict__ Wg,
                                                    const unsigned short* __restrict__ Wu,
                                                    const int* __restrict__ ptok,
                                                    const int* __restrict__ offs,
                                                    const unsigned short* __restrict__ zbuf,
                                                    unsigned short* __restrict__ H) {
  __shared__ unsigned short As[BM * BK];
  __shared__ unsigned short Bg[128 * BK];
  __shared__ unsigned short Bu[128 * BK];
  __shared__ int toks[BM];

  const int total = offs[E_];
  const int t0 = blockIdx.x * BM;
  if (t0 >= total) return;
  int e = 0;
#pragma unroll
  for (int i = 1; i < E_; ++i) if (offs[i] <= t0) e = i;

  const int tid  = threadIdx.x;
  const int lane = tid & 63;
  const int w    = tid >> 6;
  if (tid < BM) toks[tid] = ptok[t0 + tid];
  __syncthreads();

  const int ib    = blockIdx.y * 128;
  const int gcol8 = (lane & 7) ^ (lane >> 3);  // pre-swizzled source column (16B units)

  const unsigned short* asrc[2];
#pragma unroll
  for (int i = 0; i < 2; ++i) {
    int r = (w * 2 + i) * 8 + (lane >> 3);
    int t = toks[r];
    asrc[i] = (t >= 0) ? (Xb + (size_t)t * D_ + gcol8 * 8) : zbuf;
  }
  const unsigned short* bgsrc[4];
  const unsigned short* busrc[4];
#pragma unroll
  for (int i = 0; i < 4; ++i) {
    int r = (w * 4 + i) * 8 + (lane >> 3);
    size_t rowoff = ((size_t)e * I_ + ib + r) * D_ + gcol8 * 8;
    bgsrc[i] = Wg + rowoff;
    busrc[i] = Wu + rowoff;
  }

  f32x4 accg[2][4], accu[2][4];
#pragma unroll
  for (int m = 0; m < 2; ++m)
#pragma unroll
    for (int n = 0; n < 4; ++n) {
      accg[m][n] = (f32x4){0.f, 0.f, 0.f, 0.f};
      accu[m][n] = (f32x4){0.f, 0.f, 0.f, 0.f};
    }

  const int wr = w >> 1, wc = w & 1;
  const int xr7 = lane & 7;  // (frag row & 7) == lane&7 for all fragments

  for (int k0 = 0; k0 < D_; k0 += BK) {
#pragma unroll
    for (int i = 0; i < 2; ++i) GLOAD_LDS16(asrc[i] + k0, &As[(w * 2 + i) * 512]);
#pragma unroll
    for (int i = 0; i < 4; ++i) {
      GLOAD_LDS16(bgsrc[i] + k0, &Bg[(w * 4 + i) * 512]);
      GLOAD_LDS16(busrc[i] + k0, &Bu[(w * 4 + i) * 512]);
    }
    __syncthreads();  // compiler drains vmcnt before barrier
#pragma unroll
    for (int kk = 0; kk < 2; ++kk) {
      const int uoff = ((kk * 4 + (lane >> 4)) ^ xr7) * 8;
      bf16x8 a[2], bg[4], bu[4];
#pragma unroll
      for (int m = 0; m < 2; ++m) {
        int row = wr * 32 + m * 16 + (lane & 15);
        a[m] = *reinterpret_cast<const bf16x8*>(&As[row * BK + uoff]);
      }
#pragma unroll
      for (int n = 0; n < 4; ++n) {
        int row = wc * 64 + n * 16 + (lane & 15);
        bg[n] = *reinterpret_cast<const bf16x8*>(&Bg[row * BK + uoff]);
        bu[n] = *reinterpret_cast<const bf16x8*>(&Bu[row * BK + uoff]);
      }
#pragma unroll
      for (int m = 0; m < 2; ++m)
#pragma unroll
        for (int n = 0; n < 4; ++n) {
          accg[m][n] = __builtin_amdgcn_mfma_f32_16x16x32_bf16(a[m], bg[n], accg[m][n], 0, 0, 0);
          accu[m][n] = __builtin_amdgcn_mfma_f32_16x16x32_bf16(a[m], bu[n], accu[m][n], 0, 0, 0);
        }
    }
    __syncthreads();
  }

#pragma unroll
  for (int m = 0; m < 2; ++m)
#pragma unroll
    for (int n = 0; n < 4; ++n) {
      int colg = ib + wc * 64 + n * 16 + (lane & 15);
#pragma unroll
      for (int j = 0; j < 4; ++j) {
        int row = wr * 32 + m * 16 + (lane >> 4) * 4 + j;  // C/D: col=lane&15, row=(lane>>4)*4+reg (m89)
        float g = accg[m][n][j], uu = accu[m][n][j];
        float h = (g / (1.f + __expf(-g))) * uu;  // silu(g)*u
        H[(size_t)(t0 + row) * I_ + colg] = f2bf(h);
      }
    }
}

// ---------------- GEMM2: out[token] += prob * (H Wd^T) ----------------
__global__ __launch_bounds__(256) void gemm2_kernel(const unsigned short* __restrict__ H,
                                                    const unsigned short* __restrict__ Wd,
                                                    const int* __restrict__ ptok,
                                                    const float* __restrict__ pprob,
                                                    const int* __restrict__ offs,
                                                    float* __restrict__ out) {
  __shared__ unsigned short As[BM * BK];
  __shared__ unsigned short Bs[128 * BK];
  __shared__ int   toks[BM];
  __shared__ float probs[BM];

  const int total = offs[E_];
  const int t0 = blockIdx.x * BM;
  if (t0 >= total) return;
  int e = 0;
#pragma unroll
  for (int i = 1; i < E_; ++i) if (offs[i] <= t0) e = i;

  const int tid  = threadIdx.x;
  const int lane = tid & 63;
  const int w    = tid >> 6;
  if (tid < BM) { toks[tid] = ptok[t0 + tid]; probs[tid] = pprob[t0 + tid]; }
  __syncthreads();

  const int db    = blockIdx.y * 128;
  const int gcol8 = (lane & 7) ^ (lane >> 3);

  const unsigned short* asrc[2];
#pragma unroll
  for (int i = 0; i < 2; ++i) {
    int r = (w * 2 + i) * 8 + (lane >> 3);
    asrc[i] = H + (size_t)(t0 + r) * I_ + gcol8 * 8;
  }
  const unsigned short* bsrc[4];
#pragma unroll
  for (int i = 0; i < 4; ++i) {
    int r = (w * 4 + i) * 8 + (lane >> 3);
    bsrc[i] = Wd + ((size_t)e * D_ + db + r) * I_ + gcol8 * 8;
  }

  f32x4 acc[2][4];
#pragma unroll
  for (int m = 0; m < 2; ++m)
#pragma unroll
    for (int n = 0; n < 4; ++n) acc[m][n] = (f32x4){0.f, 0.f, 0.f, 0.f};

  const int wr = w >> 1, wc = w & 1;
  const int xr7 = lane & 7;

  for (int k0 = 0; k0 < I_; k0 += BK) {
#pragma unroll
    for (int i = 0; i < 2; ++i) GLOAD_LDS16(asrc[i] + k0, &As[(w * 2 + i) * 512]);
#pragma unroll
    for (int i = 0; i < 4; ++i) GLOAD_LDS16(bsrc[i] + k0, &Bs[(w * 4 + i) * 512]);
    __syncthreads();
#pragma unroll
    for (int kk = 0; kk < 2; ++kk) {
      const int uoff = ((kk * 4 + (lane >> 4)) ^ xr7) * 8;
      bf16x8 a[2], b[4];
#pragma unroll
      for (int m = 0; m < 2; ++m) {
        int row = wr * 32 + m * 16 + (lane & 15);
        a[m] = *reinterpret_cast<const bf16x8*>(&As[row * BK + uoff]);
      }
#pragma unroll
      for (int n = 0; n < 4; ++n) {
        int row = wc * 64 + n * 16 + (lane & 15);
        b[n] = *reinterpret_cast<const bf16x8*>(&Bs[row * BK + uoff]);
      }
#pragma unroll
      for (int m = 0; m < 2; ++m)
#pragma unroll
        for (int n = 0; n < 4; ++n)
          acc[m][n] = __builtin_amdgcn_mfma_f32_16x16x32_bf16(a[m], b[n], acc[m][n], 0, 0, 0);
    }
    __syncthreads();
  }

#pragma unroll
  for (int m = 0; m < 2; ++m)
#pragma unroll
    for (int n = 0; n < 4; ++n) {
      int col = db + wc * 64 + n * 16 + (lane & 15);
#pragma unroll
      for (int j = 0; j < 4; ++j) {
        int row = wr * 32 + m * 16 + (lane >> 4) * 4 + j;
        int t = toks[row];
        if (t >= 0)
          atomicAdd(&out[(size_t)t * D_ + col], acc[m][n][j] * probs[row]);
      }
    }
}

extern "C" void kernel_launch(void* const* d_in, const int* in_sizes, int n_in,
                              void* d_out, int out_size, void* d_ws, size_t ws_size,
                              hipStream_t stream) {
  const float* x  = (const float*)d_in[0];
  const float* rw = (const float*)d_in[1];
  const float* wg = (const float*)d_in[2];
  const float* wu = (const float*)d_in[3];
  const float* wd = (const float*)d_in[4];
  float* out    = (float*)d_out;
  float* logits = out + (size_t)N_TOK * D_;   // second output region

  char* ws = (char*)d_ws;
  int*   counts = (int*)(ws + 0);
  int*   cursor = (int*)(ws + 32);
  int*   offs   = (int*)(ws + 64);
  unsigned short* zbuf = (unsigned short*)(ws + 256);      // 4KB zeros
  int*   sel   = (int*)  (ws + 4352);
  float* prob  = (float*)(ws + 4352 + 32768);
  int*   ptok  = (int*)  (ws + 4352 + 65536);
  float* pprob = (float*)(ws + 4352 + 65536 + 34816);
  unsigned short* Xb  = (unsigned short*)(ws + 139520);
  unsigned short* Wgb = Xb  + (size_t)N_TOK * D_;
  unsigned short* Wub = Wgb + (size_t)E_ * I_ * D_;
  unsigned short* Wdb = Wub + (size_t)E_ * I_ * D_;
  unsigned short* Hb  = Wdb + (size_t)E_ * D_ * I_;        // [CAP, I_] bf16

  hipMemsetAsync(ws, 0, 4352, stream);                          // counts/cursor/offs + zbuf
  hipMemsetAsync(ptok, 0xFF, (size_t)CAP * 4, stream);          // -1 = padding
  hipMemsetAsync(d_out, 0, (size_t)N_TOK * D_ * 4, stream);     // out accumulates via atomics

  convert_kernel<<<4096, 256, 0, stream>>>(x,  Xb,  N_TOK * D_ / 4);
  convert_kernel<<<4096, 256, 0, stream>>>(wg, Wgb, E_ * I_ * D_ / 4);
  convert_kernel<<<4096, 256, 0, stream>>>(wu, Wub, E_ * I_ * D_ / 4);
  convert_kernel<<<4096, 256, 0, stream>>>(wd, Wdb, E_ * D_ * I_ / 4);
  router_kernel<<<N_TOK / 4, 256, 0, stream>>>(x, rw, logits, sel, prob, counts);
  offsets_kernel<<<1, 64, 0, stream>>>(counts, offs);
  scatter_kernel<<<N_TOK * KTOP / 256, 256, 0, stream>>>(sel, prob, offs, cursor, ptok, pprob);
  gemm1_kernel<<<dim3(CAP / BM, I_ / 128), 256, 0, stream>>>(Xb, Wgb, Wub, ptok, offs, zbuf, Hb);
  gemm2_kernel<<<dim3(CAP / BM, D_ / 128), 256, 0, stream>>>(Hb, Wdb, ptok, pprob, offs, out);
}

// Round 2
// 120.699 us; speedup vs baseline: 2.0213x; 2.0213x over previous
//
#include <hip/hip_runtime.h>
#include <cstdint>

// Problem constants
#define N_TOK 4096   // B*T
#define D_    1024
#define E_    8
#define I_    512
#define KTOP  2
#define BM    64     // position-tile (expert segments padded to BM)
#define BK    64     // K-step
#define CAP   (N_TOK*KTOP + E_*BM)   // 8704 max padded positions

typedef __attribute__((ext_vector_type(4))) float f32x4;
typedef __attribute__((ext_vector_type(8))) short bf16x8;

__device__ inline unsigned short f2bf(float f) {
  union { float f; uint32_t u; } v; v.f = f;
  uint32_t r = v.u + 0x7fffu + ((v.u >> 16) & 1u);
  return (unsigned short)(r >> 16);
}

// global -> LDS direct copy, 16B per lane. LDS dest is wave-uniform base,
// lane l lands at base + l*16 (m104). Global src is per-lane (enables the
// pre-swizzled-source trick, m173).
#define GLOAD_LDS16(gp, lp)                                                        \
  __builtin_amdgcn_global_load_lds((const __attribute__((address_space(1))) void*)(gp), \
                                   (__attribute__((address_space(3))) void*)(lp), 16, 0, 0)

// ---------------- fp32 -> bf16 convert (vectorized) ----------------
__global__ __launch_bounds__(256) void convert_kernel(const float* __restrict__ src,
                                                      unsigned short* __restrict__ dst,
                                                      int n4) {
  int i = blockIdx.x * 256 + threadIdx.x;
  if (i >= n4) return;
  const float4 v = reinterpret_cast<const float4*>(src)[i];
  ushort4 o;
  o.x = f2bf(v.x); o.y = f2bf(v.y); o.z = f2bf(v.z); o.w = f2bf(v.w);
  reinterpret_cast<ushort4*>(dst)[i] = o;
}

// ---------------- router: logits (fp32), top-2, softmax; fused x->bf16 ----------------
// NO atomics (R1 post-mortem: 8192 same-line atomicAdds serialized -> 103us stall).
__global__ __launch_bounds__(256) void router_kernel(const float* __restrict__ x,
                                                     const float* __restrict__ rw,
                                                     float* __restrict__ logits,
                                                     int* __restrict__ sel,
                                                     float* __restrict__ prob,
                                                     unsigned short* __restrict__ Xb) {
  const int lane = threadIdx.x & 63;
  const int tok  = blockIdx.x * 4 + (threadIdx.x >> 6);
  const float4* xr = reinterpret_cast<const float4*>(x + (size_t)tok * D_);
  float4 xv[4];
#pragma unroll
  for (int q = 0; q < 4; ++q) xv[q] = xr[q * 64 + lane];  // contiguous 1KB per instr
  float acc[E_];
#pragma unroll
  for (int e = 0; e < E_; ++e) {
    const float4* wr = reinterpret_cast<const float4*>(rw + (size_t)e * D_);
    float s = 0.f;
#pragma unroll
    for (int q = 0; q < 4; ++q) {
      float4 wv = wr[q * 64 + lane];
      s += xv[q].x * wv.x + xv[q].y * wv.y + xv[q].z * wv.z + xv[q].w * wv.w;
    }
    acc[e] = s;
  }
  // fused x -> bf16 (saves one full pass over x)
  ushort4* xb = reinterpret_cast<ushort4*>(Xb + (size_t)tok * D_);
#pragma unroll
  for (int q = 0; q < 4; ++q) {
    ushort4 o;
    o.x = f2bf(xv[q].x); o.y = f2bf(xv[q].y); o.z = f2bf(xv[q].z); o.w = f2bf(xv[q].w);
    xb[q * 64 + lane] = o;
  }
#pragma unroll
  for (int e = 0; e < E_; ++e)
#pragma unroll
    for (int off = 32; off; off >>= 1) acc[e] += __shfl_xor(acc[e], off);
  if (lane == 0) {
    float v0 = -1e30f, v1 = -1e30f; int i0 = 0, i1 = 0;
#pragma unroll
    for (int e = 0; e < E_; ++e) {
      float v = acc[e];
      logits[(size_t)tok * E_ + e] = v;
      if (v > v0)      { v1 = v0; i1 = i0; v0 = v; i0 = e; }
      else if (v > v1) { v1 = v;  i1 = e; }
    }
    float t  = __expf(v1 - v0);
    sel[tok * 2] = i0; sel[tok * 2 + 1] = i1;
    prob[tok * 2] = 1.f / (1.f + t);
    prob[tok * 2 + 1] = t / (1.f + t);
  }
}

// ---------------- plan: counts (ballot), padded offsets, scatter — zero atomics ----------------
// Single block, 16 waves x 512 entries each = 8192 (token,slot) entries.
__global__ __launch_bounds__(1024) void plan_kernel(const int* __restrict__ sel,
                                                    const float* __restrict__ prob,
                                                    int* __restrict__ offs,
                                                    int* __restrict__ ptok,
                                                    float* __restrict__ pprob) {
  __shared__ int wcnt[16][E_];
  __shared__ int pfx[16][E_];
  const int tid = threadIdx.x;
  const int wave = tid >> 6, lane = tid & 63;
  const unsigned long long lt = (1ull << lane) - 1ull;

  int   mye[8];
  int   mylp[8];
  float myp[8];
  int run[E_];
#pragma unroll
  for (int e = 0; e < E_; ++e) run[e] = 0;

#pragma unroll
  for (int it = 0; it < 8; ++it) {
    int i = wave * 512 + it * 64 + lane;
    int e = sel[i];
    mye[it] = e;
    myp[it] = prob[i];
    int lp = 0;
#pragma unroll
    for (int ee = 0; ee < E_; ++ee) {
      unsigned long long m = __ballot(e == ee);
      if (e == ee) lp = run[ee] + __popcll(m & lt);
      run[ee] += __popcll(m);     // wave-uniform
    }
    mylp[it] = lp;
  }
#pragma unroll
  for (int ee = 0; ee < E_; ++ee)
    if (lane == ee) wcnt[wave][ee] = run[ee];
  __syncthreads();

  if (tid == 0) {
    int ro = 0;
#pragma unroll
    for (int e = 0; e < E_; ++e) {
      int c = 0;
      int r = ro;
      for (int w = 0; w < 16; ++w) { pfx[w][e] = r; r += wcnt[w][e]; c += wcnt[w][e]; }
      offs[e] = ro;
      ro += (c + BM - 1) & ~(BM - 1);
    }
    offs[E_] = ro;
  }
  __syncthreads();

#pragma unroll
  for (int it = 0; it < 8; ++it) {
    int pos = pfx[wave][mye[it]] + mylp[it];
    ptok[pos]  = (wave * 512 + it * 64 + lane) >> 1;
    pprob[pos] = myp[it];
  }
}

// ---------------- GEMM1: H = silu(X Wg^T) * (X Wu^T), per expert segment ----------------
__global__ __launch_bounds__(256) void gemm1_kernel(const unsigned short* __restrict__ Xb,
                                                    const unsigned short* __restrict__ Wg,
                                                    const unsigned short* __restrict__ Wu,
                                                    const int* __restrict__ ptok,
                                                    const int* __restrict__ offs,
                                                    const unsigned short* __restrict__ zbuf,
                                                    unsigned short* __restrict__ H) {
  __shared__ unsigned short As[BM * BK];
  __shared__ unsigned short Bg[128 * BK];
  __shared__ unsigned short Bu[128 * BK];
  __shared__ int toks[BM];

  const int total = offs[E_];
  const int t0 = blockIdx.x * BM;
  if (t0 >= total) return;
  int e = 0;
#pragma unroll
  for (int i = 1; i < E_; ++i) if (offs[i] <= t0) e = i;

  const int tid  = threadIdx.x;
  const int lane = tid & 63;
  const int w    = tid >> 6;
  if (tid < BM) toks[tid] = ptok[t0 + tid];
  __syncthreads();

  const int ib    = blockIdx.y * 128;
  const int gcol8 = (lane & 7) ^ (lane >> 3);  // pre-swizzled source column (16B units)

  const unsigned short* asrc[2];
#pragma unroll
  for (int i = 0; i < 2; ++i) {
    int r = (w * 2 + i) * 8 + (lane >> 3);
    int t = toks[r];
    asrc[i] = (t >= 0) ? (Xb + (size_t)t * D_ + gcol8 * 8) : zbuf;
  }
  const unsigned short* bgsrc[4];
  const unsigned short* busrc[4];
#pragma unroll
  for (int i = 0; i < 4; ++i) {
    int r = (w * 4 + i) * 8 + (lane >> 3);
    size_t rowoff = ((size_t)e * I_ + ib + r) * D_ + gcol8 * 8;
    bgsrc[i] = Wg + rowoff;
    busrc[i] = Wu + rowoff;
  }

  f32x4 accg[2][4], accu[2][4];
#pragma unroll
  for (int m = 0; m < 2; ++m)
#pragma unroll
    for (int n = 0; n < 4; ++n) {
      accg[m][n] = (f32x4){0.f, 0.f, 0.f, 0.f};
      accu[m][n] = (f32x4){0.f, 0.f, 0.f, 0.f};
    }

  const int wr = w >> 1, wc = w & 1;
  const int xr7 = lane & 7;

  for (int k0 = 0; k0 < D_; k0 += BK) {
#pragma unroll
    for (int i = 0; i < 2; ++i) GLOAD_LDS16(asrc[i] + k0, &As[(w * 2 + i) * 512]);
#pragma unroll
    for (int i = 0; i < 4; ++i) {
      GLOAD_LDS16(bgsrc[i] + k0, &Bg[(w * 4 + i) * 512]);
      GLOAD_LDS16(busrc[i] + k0, &Bu[(w * 4 + i) * 512]);
    }
    __syncthreads();
#pragma unroll
    for (int kk = 0; kk < 2; ++kk) {
      const int uoff = ((kk * 4 + (lane >> 4)) ^ xr7) * 8;
      bf16x8 a[2], bg[4], bu[4];
#pragma unroll
      for (int m = 0; m < 2; ++m) {
        int row = wr * 32 + m * 16 + (lane & 15);
        a[m] = *reinterpret_cast<const bf16x8*>(&As[row * BK + uoff]);
      }
#pragma unroll
      for (int n = 0; n < 4; ++n) {
        int row = wc * 64 + n * 16 + (lane & 15);
        bg[n] = *reinterpret_cast<const bf16x8*>(&Bg[row * BK + uoff]);
        bu[n] = *reinterpret_cast<const bf16x8*>(&Bu[row * BK + uoff]);
      }
#pragma unroll
      for (int m = 0; m < 2; ++m)
#pragma unroll
        for (int n = 0; n < 4; ++n) {
          accg[m][n] = __builtin_amdgcn_mfma_f32_16x16x32_bf16(a[m], bg[n], accg[m][n], 0, 0, 0);
          accu[m][n] = __builtin_amdgcn_mfma_f32_16x16x32_bf16(a[m], bu[n], accu[m][n], 0, 0, 0);
        }
    }
    __syncthreads();
  }

#pragma unroll
  for (int m = 0; m < 2; ++m)
#pragma unroll
    for (int n = 0; n < 4; ++n) {
      int colg = ib + wc * 64 + n * 16 + (lane & 15);
#pragma unroll
      for (int j = 0; j < 4; ++j) {
        int row = wr * 32 + m * 16 + (lane >> 4) * 4 + j;  // C/D: col=lane&15, row=(lane>>4)*4+reg (m89)
        float g = accg[m][n][j], uu = accu[m][n][j];
        float h = (g / (1.f + __expf(-g))) * uu;  // silu(g)*u
        H[(size_t)(t0 + row) * I_ + colg] = f2bf(h);
      }
    }
}

// ---------------- GEMM2: out[token] += prob * (H Wd^T) ----------------
__global__ __launch_bounds__(256) void gemm2_kernel(const unsigned short* __restrict__ H,
                                                    const unsigned short* __restrict__ Wd,
                                                    const int* __restrict__ ptok,
                                                    const float* __restrict__ pprob,
                                                    const int* __restrict__ offs,
                                                    float* __restrict__ out) {
  __shared__ unsigned short As[BM * BK];
  __shared__ unsigned short Bs[128 * BK];
  __shared__ int   toks[BM];
  __shared__ float probs[BM];

  const int total = offs[E_];
  const int t0 = blockIdx.x * BM;
  if (t0 >= total) return;
  int e = 0;
#pragma unroll
  for (int i = 1; i < E_; ++i) if (offs[i] <= t0) e = i;

  const int tid  = threadIdx.x;
  const int lane = tid & 63;
  const int w    = tid >> 6;
  if (tid < BM) { toks[tid] = ptok[t0 + tid]; probs[tid] = pprob[t0 + tid]; }
  __syncthreads();

  const int db    = blockIdx.y * 128;
  const int gcol8 = (lane & 7) ^ (lane >> 3);

  const unsigned short* asrc[2];
#pragma unroll
  for (int i = 0; i < 2; ++i) {
    int r = (w * 2 + i) * 8 + (lane >> 3);
    asrc[i] = H + (size_t)(t0 + r) * I_ + gcol8 * 8;
  }
  const unsigned short* bsrc[4];
#pragma unroll
  for (int i = 0; i < 4; ++i) {
    int r = (w * 4 + i) * 8 + (lane >> 3);
    bsrc[i] = Wd + ((size_t)e * D_ + db + r) * I_ + gcol8 * 8;
  }

  f32x4 acc[2][4];
#pragma unroll
  for (int m = 0; m < 2; ++m)
#pragma unroll
    for (int n = 0; n < 4; ++n) acc[m][n] = (f32x4){0.f, 0.f, 0.f, 0.f};

  const int wr = w >> 1, wc = w & 1;
  const int xr7 = lane & 7;

  for (int k0 = 0; k0 < I_; k0 += BK) {
#pragma unroll
    for (int i = 0; i < 2; ++i) GLOAD_LDS16(asrc[i] + k0, &As[(w * 2 + i) * 512]);
#pragma unroll
    for (int i = 0; i < 4; ++i) GLOAD_LDS16(bsrc[i] + k0, &Bs[(w * 4 + i) * 512]);
    __syncthreads();
#pragma unroll
    for (int kk = 0; kk < 2; ++kk) {
      const int uoff = ((kk * 4 + (lane >> 4)) ^ xr7) * 8;
      bf16x8 a[2], b[4];
#pragma unroll
      for (int m = 0; m < 2; ++m) {
        int row = wr * 32 + m * 16 + (lane & 15);
        a[m] = *reinterpret_cast<const bf16x8*>(&As[row * BK + uoff]);
      }
#pragma unroll
      for (int n = 0; n < 4; ++n) {
        int row = wc * 64 + n * 16 + (lane & 15);
        b[n] = *reinterpret_cast<const bf16x8*>(&Bs[row * BK + uoff]);
      }
#pragma unroll
      for (int m = 0; m < 2; ++m)
#pragma unroll
        for (int n = 0; n < 4; ++n)
          acc[m][n] = __builtin_amdgcn_mfma_f32_16x16x32_bf16(a[m], b[n], acc[m][n], 0, 0, 0);
    }
    __syncthreads();
  }

#pragma unroll
  for (int m = 0; m < 2; ++m)
#pragma unroll
    for (int n = 0; n < 4; ++n) {
      int col = db + wc * 64 + n * 16 + (lane & 15);
#pragma unroll
      for (int j = 0; j < 4; ++j) {
        int row = wr * 32 + m * 16 + (lane >> 4) * 4 + j;
        int t = toks[row];
        if (t >= 0)
          atomicAdd(&out[(size_t)t * D_ + col], acc[m][n][j] * probs[row]);
      }
    }
}

extern "C" void kernel_launch(void* const* d_in, const int* in_sizes, int n_in,
                              void* d_out, int out_size, void* d_ws, size_t ws_size,
                              hipStream_t stream) {
  const float* x  = (const float*)d_in[0];
  const float* rw = (const float*)d_in[1];
  const float* wg = (const float*)d_in[2];
  const float* wu = (const float*)d_in[3];
  const float* wd = (const float*)d_in[4];
  float* out    = (float*)d_out;
  float* logits = out + (size_t)N_TOK * D_;   // second output region

  char* ws = (char*)d_ws;
  int*   offs  = (int*)(ws + 64);
  unsigned short* zbuf = (unsigned short*)(ws + 256);       // 4KB zeros
  int*   sel   = (int*)  (ws + 4352);
  float* prob  = (float*)(ws + 4352 + 32768);
  int*   ptok  = (int*)  (ws + 69888);
  float* pprob = (float*)(ws + 104704);
  unsigned short* Xb  = (unsigned short*)(ws + 139520);
  unsigned short* Wgb = Xb  + (size_t)N_TOK * D_;
  unsigned short* Wub = Wgb + (size_t)E_ * I_ * D_;
  unsigned short* Wdb = Wub + (size_t)E_ * I_ * D_;
  unsigned short* Hb  = Wdb + (size_t)E_ * D_ * I_;         // [CAP, I_] bf16

  hipMemsetAsync(ws, 0, 4352, stream);                          // offs + zbuf
  hipMemsetAsync(ptok, 0xFF, (size_t)CAP * 4, stream);          // -1 = padding
  hipMemsetAsync(d_out, 0, (size_t)N_TOK * D_ * 4, stream);     // out accumulates via atomics

  convert_kernel<<<4096, 256, 0, stream>>>(wg, Wgb, E_ * I_ * D_ / 4);
  convert_kernel<<<4096, 256, 0, stream>>>(wu, Wub, E_ * I_ * D_ / 4);
  convert_kernel<<<4096, 256, 0, stream>>>(wd, Wdb, E_ * D_ * I_ / 4);
  router_kernel<<<N_TOK / 4, 256, 0, stream>>>(x, rw, logits, sel, prob, Xb);
  plan_kernel<<<1, 1024, 0, stream>>>(sel, prob, offs, ptok, pprob);
  gemm1_kernel<<<dim3(CAP / BM, I_ / 128), 256, 0, stream>>>(Xb, Wgb, Wub, ptok, offs, zbuf, Hb);
  gemm2_kernel<<<dim3(CAP / BM, D_ / 128), 256, 0, stream>>>(Hb, Wdb, ptok, pprob, offs, out);
}